// Round 2
// baseline (61.179 us; speedup 1.0000x reference)
//
#include <hip/hip_runtime.h>

// SparsityLoss: out = THETA * sum(where(valid, masks, 0)) / (I*(J-1)*K)
// I=128, J=49, K=4096  -> n = 25,690,112 elements.
// masks: fp32 (102.8 MB). valid: int32 on device (102.8 MB) — harness converts
// bool -> int32 (round-1 evidence: byte-wise read gave exactly 1/4 of the sum).
// Memory-bound reduction (~205.6 MB). Double accumulation for precision.

static constexpr double kTheta = 0.0001;
static constexpr int kI = 128;
static constexpr int kJ = 49;
static constexpr int kK = 4096;

__global__ __launch_bounds__(256) void sparsity_reduce_kernel(
    const float4* __restrict__ masks4,
    const int4* __restrict__ valid4,   // 4 int32 flags per load
    double* __restrict__ acc,
    int n4,                            // number of 4-element groups
    const float* __restrict__ masks_tail,
    const int* __restrict__ valid_tail,
    int n_tail) {
    double local = 0.0;
    const int stride = gridDim.x * blockDim.x;
    for (int i = blockIdx.x * blockDim.x + threadIdx.x; i < n4; i += stride) {
        float4 m = masks4[i];
        int4 v = valid4[i];
        float s = 0.0f;
        if (v.x) s += m.x;
        if (v.y) s += m.y;
        if (v.z) s += m.z;
        if (v.w) s += m.w;
        local += (double)s;
    }
    // Tail (n % 4 != 0) — n = 25,690,112 is divisible by 4, so this is empty.
    if (blockIdx.x == 0 && threadIdx.x == 0) {
        for (int i = 0; i < n_tail; ++i) {
            if (valid_tail[i]) local += (double)masks_tail[i];
        }
    }

    // Wave-64 reduction.
    for (int off = 32; off > 0; off >>= 1) {
        local += __shfl_down(local, off, 64);
    }
    __shared__ double wave_sums[4];  // 256 threads = 4 waves
    const int lane = threadIdx.x & 63;
    const int wid = threadIdx.x >> 6;
    if (lane == 0) wave_sums[wid] = local;
    __syncthreads();
    if (threadIdx.x == 0) {
        double s = wave_sums[0] + wave_sums[1] + wave_sums[2] + wave_sums[3];
        atomicAdd(acc, s);  // device-scope f64 atomic, one per block
    }
}

__global__ void sparsity_finalize_kernel(const double* __restrict__ acc,
                                         float* __restrict__ out) {
    const double denom = (double)kI * (double)(kJ - 1) * (double)kK;
    out[0] = (float)(kTheta * acc[0] / denom);
}

extern "C" void kernel_launch(void* const* d_in, const int* in_sizes, int n_in,
                              void* d_out, int out_size, void* d_ws, size_t ws_size,
                              hipStream_t stream) {
    const float* masks = (const float*)d_in[0];
    const int* valid = (const int*)d_in[1];
    const int n = in_sizes[0];

    const int n4 = n / 4;
    const int n_tail = n - n4 * 4;

    double* acc = (double*)d_ws;
    hipMemsetAsync(acc, 0, sizeof(double), stream);  // ws not re-zeroed between replays

    const int block = 256;
    int grid = (n4 + block - 1) / block;
    if (grid > 2048) grid = 2048;
    if (grid < 1) grid = 1;

    sparsity_reduce_kernel<<<grid, block, 0, stream>>>(
        (const float4*)masks, (const int4*)valid, acc, n4,
        masks + n4 * 4, valid + n4 * 4, n_tail);

    sparsity_finalize_kernel<<<1, 1, 0, stream>>>(acc, (float*)d_out);
}

// Round 3
// 41.182 us; speedup vs baseline: 1.4856x; 1.4856x over previous
//
#include <hip/hip_runtime.h>

// SparsityLoss: out = THETA * sum(where(valid, masks, 0)) / (I*(J-1)*K)
// I=128, J=49, K=4096 -> n = 25,690,112 elements.
// masks: fp32 (102.8 MB). valid: int32 (102.8 MB).
// Round-2 evidence: inputs are L3-resident on replays (hbm_bytes~0) yet the
// kernel took 83 us with VALUBusy 3.8% -> bound by 2048 same-address f64
// atomics (~40ns each, serialized). Fix: two-stage reduction, no atomics,
// plus 4x unroll for memory-level parallelism.

static constexpr double kTheta = 0.0001;
static constexpr int kI = 128;
static constexpr int kJ = 49;
static constexpr int kK = 4096;
static constexpr int kBlocks = 2048;   // 8 blocks/CU * 256 CUs
static constexpr int kBlockSize = 256;

__global__ __launch_bounds__(kBlockSize) void sparsity_partial_kernel(
    const float4* __restrict__ masks4,
    const int4* __restrict__ valid4,
    double* __restrict__ block_sums,
    int n4,
    const float* __restrict__ masks_tail,
    const int* __restrict__ valid_tail,
    int n_tail) {
    const int tid = blockIdx.x * blockDim.x + threadIdx.x;
    const int stride = gridDim.x * blockDim.x;

    double local = 0.0;
    int i = tid;
    // 4x unrolled main loop: 8 independent 16B loads in flight.
    for (; i + 3 * stride < n4; i += 4 * stride) {
        float4 m0 = masks4[i];
        float4 m1 = masks4[i + stride];
        float4 m2 = masks4[i + 2 * stride];
        float4 m3 = masks4[i + 3 * stride];
        int4 v0 = valid4[i];
        int4 v1 = valid4[i + stride];
        int4 v2 = valid4[i + 2 * stride];
        int4 v3 = valid4[i + 3 * stride];
        float s0 = (v0.x ? m0.x : 0.0f) + (v0.y ? m0.y : 0.0f) +
                   (v0.z ? m0.z : 0.0f) + (v0.w ? m0.w : 0.0f);
        float s1 = (v1.x ? m1.x : 0.0f) + (v1.y ? m1.y : 0.0f) +
                   (v1.z ? m1.z : 0.0f) + (v1.w ? m1.w : 0.0f);
        float s2 = (v2.x ? m2.x : 0.0f) + (v2.y ? m2.y : 0.0f) +
                   (v2.z ? m2.z : 0.0f) + (v2.w ? m2.w : 0.0f);
        float s3 = (v3.x ? m3.x : 0.0f) + (v3.y ? m3.y : 0.0f) +
                   (v3.z ? m3.z : 0.0f) + (v3.w ? m3.w : 0.0f);
        local += (double)s0 + (double)s1 + (double)s2 + (double)s3;
    }
    // Remainder strides.
    for (; i < n4; i += stride) {
        float4 m = masks4[i];
        int4 v = valid4[i];
        float s = (v.x ? m.x : 0.0f) + (v.y ? m.y : 0.0f) +
                  (v.z ? m.z : 0.0f) + (v.w ? m.w : 0.0f);
        local += (double)s;
    }
    // Scalar tail (n % 4): empty for n = 25,690,112.
    if (blockIdx.x == 0 && threadIdx.x == 0) {
        for (int t = 0; t < n_tail; ++t) {
            if (valid_tail[t]) local += (double)masks_tail[t];
        }
    }

    // Wave-64 shuffle reduction.
    for (int off = 32; off > 0; off >>= 1) {
        local += __shfl_down(local, off, 64);
    }
    __shared__ double wave_sums[kBlockSize / 64];
    const int lane = threadIdx.x & 63;
    const int wid = threadIdx.x >> 6;
    if (lane == 0) wave_sums[wid] = local;
    __syncthreads();
    if (threadIdx.x == 0) {
        double s = wave_sums[0] + wave_sums[1] + wave_sums[2] + wave_sums[3];
        block_sums[blockIdx.x] = s;   // one plain store per block, no atomics
    }
}

__global__ __launch_bounds__(kBlockSize) void sparsity_finalize_kernel(
    const double* __restrict__ block_sums, int nblocks,
    float* __restrict__ out) {
    double local = 0.0;
    for (int i = threadIdx.x; i < nblocks; i += kBlockSize) {
        local += block_sums[i];
    }
    for (int off = 32; off > 0; off >>= 1) {
        local += __shfl_down(local, off, 64);
    }
    __shared__ double wave_sums[kBlockSize / 64];
    const int lane = threadIdx.x & 63;
    const int wid = threadIdx.x >> 6;
    if (lane == 0) wave_sums[wid] = local;
    __syncthreads();
    if (threadIdx.x == 0) {
        double s = wave_sums[0] + wave_sums[1] + wave_sums[2] + wave_sums[3];
        const double denom = (double)kI * (double)(kJ - 1) * (double)kK;
        out[0] = (float)(kTheta * s / denom);
    }
}

extern "C" void kernel_launch(void* const* d_in, const int* in_sizes, int n_in,
                              void* d_out, int out_size, void* d_ws, size_t ws_size,
                              hipStream_t stream) {
    const float* masks = (const float*)d_in[0];
    const int* valid = (const int*)d_in[1];
    const int n = in_sizes[0];

    const int n4 = n / 4;
    const int n_tail = n - n4 * 4;

    double* block_sums = (double*)d_ws;  // kBlocks doubles = 16 KB scratch

    sparsity_partial_kernel<<<kBlocks, kBlockSize, 0, stream>>>(
        (const float4*)masks, (const int4*)valid, block_sums, n4,
        masks + n4 * 4, valid + n4 * 4, n_tail);

    sparsity_finalize_kernel<<<1, kBlockSize, 0, stream>>>(
        block_sums, kBlocks, (float*)d_out);
}